// Round 4
// baseline (46.955 us; speedup 1.0000x reference)
//
#include <hip/hip_runtime.h>

#define NC 2048
#define D 64
#define H 32

// ---------------- K1: segment bounds (owner sorted ascending) -------------
__global__ void bounds_kernel(const int* __restrict__ owner,
                              int* __restrict__ bounds, int n) {
    int i = blockIdx.x * blockDim.x + threadIdx.x;
    if (i >= n) return;
    int o  = owner[i];
    int op = (i == 0) ? -1 : owner[i - 1];
    for (int g = op + 1; g <= o; ++g) bounds[g] = i;
    if (i == n - 1)
        for (int g = o + 1; g <= NC; ++g) bounds[g] = n;
}

// ---------------- K2: fully-fused per-crystal kernel ----------------------
// Block = 1 crystal, 256 threads = 4 waves, waves stride atoms by 4.
// Lane = (dg = lane>>5, h = lane&31). Registers hold:
//   wkr[32] = Wk[dg*32 .. dg*32+31][h]   (constant across atoms)
//   acc[32] = output slice out[g][dg*32+j][h]
// Per atom: 8x float4 fea loads -> 32 FMA logit partial -> shfl_xor(32)
// cross-half reduce -> exp -> p lands in exactly the lane that needs it
// for the outer product. Per-lane running sum of p IS the denominator.
// Softmax shift-invariance => no max subtraction (|w| <~ 6, f32-safe;
// validated by R2/R3 absmax 0.0078 vs threshold 0.0478).
__global__ __launch_bounds__(256) void crystal_kernel(
    const float* __restrict__ atom_feas,
    const float* __restrict__ Wk,
    const float* __restrict__ bk,
    const int* __restrict__ bounds,
    float* __restrict__ out)
{
    __shared__ float part[3][64][34];   // waves 1..3 partials: 26.1 KB

    const int g    = blockIdx.x;
    const int tid  = threadIdx.x;
    const int lane = tid & 63;
    const int wv   = tid >> 6;
    const int h    = lane & 31;
    const int dg   = lane >> 5;
    const int d0   = dg * 32;

    // Wk column slice -> registers (coalesced: per instr, 2x128B rows)
    float wkr[32];
    #pragma unroll
    for (int j = 0; j < 32; ++j) wkr[j] = Wk[(d0 + j) * H + h];
    const float bkv = bk[h];

    const int s = bounds[g];
    const int e = bounds[g + 1];

    float acc[32];
    #pragma unroll
    for (int j = 0; j < 32; ++j) acc[j] = 0.f;
    float es = 0.f;

    float4 b0[8], b1[8];

    auto compute = [&](const float4* f) {
        float partial = 0.f;
        #pragma unroll
        for (int j = 0; j < 8; ++j) {
            partial += f[j].x * wkr[4 * j + 0];
            partial += f[j].y * wkr[4 * j + 1];
            partial += f[j].z * wkr[4 * j + 2];
            partial += f[j].w * wkr[4 * j + 3];
        }
        const float w = partial + __shfl_xor(partial, 32, 64) + bkv;
        const float p = __expf(w);
        es += p;
        #pragma unroll
        for (int j = 0; j < 8; ++j) {
            acc[4 * j + 0] += f[j].x * p;
            acc[4 * j + 1] += f[j].y * p;
            acc[4 * j + 2] += f[j].z * p;
            acc[4 * j + 3] += f[j].w * p;
        }
    };

    int a = s + wv;
    if (a < e) {
        {
            const float4* fp = (const float4*)(atom_feas + (size_t)a * D + d0);
            #pragma unroll
            for (int j = 0; j < 8; ++j) b0[j] = fp[j];
        }
        int nxt = a + 4;
        for (;;) {
            if (nxt < e) {            // prefetch into b1 while computing b0
                const float4* fp = (const float4*)(atom_feas + (size_t)nxt * D + d0);
                #pragma unroll
                for (int j = 0; j < 8; ++j) b1[j] = fp[j];
            }
            compute(b0);
            a = nxt;
            if (a >= e) break;
            nxt = a + 4;
            if (nxt < e) {            // prefetch into b0 while computing b1
                const float4* fp = (const float4*)(atom_feas + (size_t)nxt * D + d0);
                #pragma unroll
                for (int j = 0; j < 8; ++j) b0[j] = fp[j];
            }
            compute(b1);
            a = nxt;
            if (a >= e) break;
            nxt = a + 4;
        }
    }

    // ---- cross-wave combine (once per block)
    if (wv > 0) {
        #pragma unroll
        for (int j = 0; j < 32; ++j) part[wv - 1][lane][j] = acc[j];
        part[wv - 1][lane][32] = es;
    }
    __syncthreads();
    if (wv == 0) {
        #pragma unroll
        for (int j = 0; j < 32; ++j)
            acc[j] += part[0][lane][j] + part[1][lane][j] + part[2][lane][j];
        es += part[0][lane][32] + part[1][lane][32] + part[2][lane][32];
        const float inv = (es > 0.f) ? 1.0f / es : 0.f;
        float* og = out + (size_t)g * (D * H);
        #pragma unroll
        for (int j = 0; j < 32; ++j)
            og[(d0 + j) * H + h] = acc[j] * inv;   // per instr: 2x128B, coalesced
    }
}

// ---------------- Fallback (ws too small): known-good fused kernel --------
#define CHUNK 64
__global__ __launch_bounds__(256) void fused_kernel(
    const float* __restrict__ atom_feas,
    const float* __restrict__ Wk,
    const float* __restrict__ bk,
    const int* __restrict__ owner,
    float* __restrict__ out,
    int n_atoms)
{
    __shared__ float fea_lds[CHUNK * D];
    __shared__ float w_lds[CHUNK * H];
    __shared__ float wk_lds[D * H];
    __shared__ float bk_lds[H];

    const int g   = blockIdx.x;
    const int tid = threadIdx.x;
    const int h   = tid & 31;
    const int grp = tid >> 5;

    for (int i = tid; i < D * H; i += 256) wk_lds[i] = Wk[i];
    if (tid < H) bk_lds[tid] = bk[tid];

    int lo = 0, hi = n_atoms;
    while (lo < hi) { int mid = (lo + hi) >> 1; if (owner[mid] < g) lo = mid + 1; else hi = mid; }
    const int seg_start = lo;
    hi = n_atoms;
    while (lo < hi) { int mid = (lo + hi) >> 1; if (owner[mid] < g + 1) lo = mid + 1; else hi = mid; }
    const int seg_end = lo;

    float acc[8];
    #pragma unroll
    for (int j = 0; j < 8; ++j) acc[j] = 0.f;
    float ps = 0.f;

    __syncthreads();

    for (int base = seg_start; base < seg_end; base += CHUNK) {
        const int na = min(CHUNK, seg_end - base);
        {
            const int nf4 = na * (D / 4);
            const float4* src = (const float4*)(atom_feas + (size_t)base * D);
            float4* dst = (float4*)fea_lds;
            for (int i = tid; i < nf4; i += 256) dst[i] = src[i];
        }
        __syncthreads();

        for (int pi = tid; pi < na * H; pi += 256) {
            const int a  = pi >> 5;
            const int hh = pi & 31;
            const float* fr = fea_lds + a * D;
            float wvl = bk_lds[hh];
            #pragma unroll
            for (int k = 0; k < D; k += 4) {
                float4 f = *(const float4*)(fr + k);
                wvl += f.x * wk_lds[(k + 0) * H + hh];
                wvl += f.y * wk_lds[(k + 1) * H + hh];
                wvl += f.z * wk_lds[(k + 2) * H + hh];
                wvl += f.w * wk_lds[(k + 3) * H + hh];
            }
            w_lds[pi] = __expf(wvl);
        }
        __syncthreads();

        for (int a = 0; a < na; ++a) {
            const float p = w_lds[a * H + h];
            ps += p;
            const float* f = fea_lds + a * D + grp * 8;
            #pragma unroll
            for (int j = 0; j < 8; ++j) acc[j] += f[j] * p;
        }
        __syncthreads();
    }

    const float inv = (ps > 0.f) ? 1.0f / ps : 0.f;
    float* og = out + (size_t)g * (D * H);
    #pragma unroll
    for (int j = 0; j < 8; ++j) og[(grp * 8 + j) * H + h] = acc[j] * inv;
}

extern "C" void kernel_launch(void* const* d_in, const int* in_sizes, int n_in,
                              void* d_out, int out_size, void* d_ws, size_t ws_size,
                              hipStream_t stream) {
    const float* atom_feas = (const float*)d_in[0];
    const float* Wk        = (const float*)d_in[1];
    const float* bk        = (const float*)d_in[2];
    // d_in[3] = atomic_numbers (unused by the reference)
    const int*   owner     = (const int*)d_in[4];
    const int n_atoms = in_sizes[4];
    float* out = (float*)d_out;

    if (ws_size >= (NC + 1) * sizeof(int)) {
        int* bounds = (int*)d_ws;
        bounds_kernel<<<(n_atoms + 255) / 256, 256, 0, stream>>>(owner, bounds, n_atoms);
        crystal_kernel<<<NC, 256, 0, stream>>>(atom_feas, Wk, bk, bounds, out);
    } else {
        fused_kernel<<<NC, 256, 0, stream>>>(atom_feas, Wk, bk, owner, out, n_atoms);
    }
}